// Round 11
// baseline (176.893 us; speedup 1.0000x reference)
//
#include <hip/hip_runtime.h>

#define NN 100000
#define SS 50000
#define KK 32
#define CC 128
#define RPB 160          // rows per proj block; 625 * 160 = 100000
#define LDA 136          // LDS row stride in halfs (272 B = 17*16, b128-aligned)
#define PTHR 1e-8f       // agg fetch filter: p_raw below this contributes
                         // <= 32*1e-8*|v|max ~ 5e-6 after normalization

typedef _Float16 f16x8 __attribute__((ext_vector_type(8)));
typedef _Float16 f16x4 __attribute__((ext_vector_type(4)));
typedef _Float16 f16x2 __attribute__((ext_vector_type(2)));
typedef float f32x4 __attribute__((ext_vector_type(4)));

// Butterfly-sum steps as DPP: the lane exchange rides the VALU add as a
// source modifier -- no DS-pipe op, no address math, 1 instruction/step.
// Valid because every wave is fully active (grid maps waves 1:1 to s).
template<int CTRL>
__device__ __forceinline__ float dpp_add(float x) {
    const int m = __builtin_amdgcn_update_dpp(0, __float_as_int(x),
                                              CTRL, 0xF, 0xF, true);
    return x + __int_as_float(m);
}

// xor16 lane exchange: single-instruction ds_swizzle BitMode.
#define SWZ_X16 0x401F
__device__ __forceinline__ float swz16(float x) {
    return __int_as_float(__builtin_amdgcn_ds_swizzle(__float_as_int(x), SWZ_X16));
}

// Workspace table T: per row i (512 B stride, 256 halfs):
//   T[i*256 +   0 .. 127] = fp16(word_vec[i])   (proj staging loop)
//   T[i*256 + 128 .. 255] = fp16(P[i])          (proj epilogue)

// ---------------------------------------------------------------------------
// Kernel 1 (fused convert+proj): unchanged R6 proj (best measured).
// ---------------------------------------------------------------------------
__global__ __launch_bounds__(256) void proj_kernel(
    const float* __restrict__ wv,
    const float* __restrict__ W,
    const float* __restrict__ bias,
    _Float16* __restrict__ T,
    float* __restrict__ out)
{
    __shared__ _Float16 sA[RPB][LDA];

    const int t = threadIdx.x;
    const int base = blockIdx.x * RPB;

    // Stage A (160 x 128 fp32 -> fp16 LDS + T copy). 20 float4 per thread.
    #pragma unroll 4
    for (int i = 0; i < 20; i++) {
        const int idx = i * 256 + t;
        const int row = idx >> 5;
        const int c4 = (idx & 31) * 4;
        const float4 v = *(const float4*)(wv + (size_t)(base + row) * CC + c4);
        f16x4 h;
        h[0] = (_Float16)v.x; h[1] = (_Float16)v.y;
        h[2] = (_Float16)v.z; h[3] = (_Float16)v.w;
        *(f16x4*)&sA[row][c4] = h;
        *(f16x4*)(T + (size_t)(base + row) * 256 + c4) = h;
    }

    const int w = t >> 6;
    const int l = t & 63;
    const int q = l >> 4;      // quad 0..3
    const int c = l & 15;

    // B-frags: B[k][n] = W[n][k]; lane holds n = w*32+nch*16+c, k = kc*32+q*8+j
    f16x8 bf[2][4];
    float bo[2];
    #pragma unroll
    for (int nch = 0; nch < 2; nch++) {
        const int n = w * 32 + nch * 16 + c;
        bo[nch] = bias[n];
        const float* Wr = W + (size_t)n * CC;
        #pragma unroll
        for (int kc = 0; kc < 4; kc++) {
            const int k0 = kc * 32 + q * 8;
            const float4 w0 = *(const float4*)(Wr + k0);
            const float4 w1 = *(const float4*)(Wr + k0 + 4);
            f16x8 b;
            b[0] = (_Float16)w0.x; b[1] = (_Float16)w0.y;
            b[2] = (_Float16)w0.z; b[3] = (_Float16)w0.w;
            b[4] = (_Float16)w1.x; b[5] = (_Float16)w1.y;
            b[6] = (_Float16)w1.z; b[7] = (_Float16)w1.w;
            bf[nch][kc] = b;
        }
    }
    __syncthreads();

    #pragma unroll 2
    for (int sub = 0; sub < RPB / 16; sub++) {
        const int rl = sub * 16 + c;

        f16x8 af[4];
        #pragma unroll
        for (int kc = 0; kc < 4; kc++)
            af[kc] = *(const f16x8*)&sA[rl][kc * 32 + q * 8];

        f32x4 acc[2] = {{0.f, 0.f, 0.f, 0.f}, {0.f, 0.f, 0.f, 0.f}};
        #pragma unroll
        for (int kc = 0; kc < 4; kc++) {
            acc[0] = __builtin_amdgcn_mfma_f32_16x16x32_f16(af[kc], bf[0][kc], acc[0], 0, 0, 0);
            acc[1] = __builtin_amdgcn_mfma_f32_16x16x32_f16(af[kc], bf[1][kc], acc[1], 0, 0, 0);
        }

        // D layout: col = c (+tile offset), row = q*4 + reg.
        #pragma unroll
        for (int nch = 0; nch < 2; nch++) {
            const int col = w * 32 + nch * 16 + c;
            #pragma unroll
            for (int r = 0; r < 4; r++) {
                const int row = base + sub * 16 + q * 4 + r;
                float v = acc[nch][r] + bo[nch];
                v = v > 0.f ? v : 0.2f * v;
                out[(size_t)row * CC + col] = v;
                T[(size_t)row * 256 + 128 + col] = (_Float16)v;
            }
        }
    }
}

// ---------------------------------------------------------------------------
// Kernel 2: one wave per s, lane = r*16+c. R11 = EXACT R8 attn (last pass,
// 47.5 us) with ONE change -- the contiguous index prologue (piece (c) of
// the R9 bundle): lane (r,c) owns channels k = r*8..r*8+7, so its 8 neighbor
// indices and 8 mask words load as 4 dwordx4 -- no ballot, no ds_bpermute,
// no bit-extract chain. k-remap is a softmax-set permutation (downstream is
// mapping-agnostic: reductions span all 32 via sum-over-ch x r-butterfly;
// the write depends only on (r,c)). Everything downstream of nbv/mbits is
// byte-identical R8 code. Single-variable bisection of the R9/R10 failure.
// ---------------------------------------------------------------------------
__global__ __launch_bounds__(256, 8) void attn_kernel(
    const _Float16* __restrict__ T,
    const int* __restrict__ src_idx,
    const int* __restrict__ neighs,
    const int* __restrict__ mask,
    float* __restrict__ out)
{
    const int s = (blockIdx.x * 256 + threadIdx.x) >> 6;
    if (s >= SS) return;
    const int lane = threadIdx.x & 63;
    const int c = lane & 15;
    const int r = lane >> 4;

    // Contiguous index prologue: lane (r,c) owns k = r*8 .. r*8+7.
    const int* nrow = neighs + s * KK + r * 8;
    const int* mrow = mask   + s * KK + r * 8;
    const int4 nb0 = *(const int4*)(nrow);
    const int4 nb1 = *(const int4*)(nrow + 4);
    const int4 mk0 = *(const int4*)(mrow);
    const int4 mk1 = *(const int4*)(mrow + 4);
    const int src = src_idx[s];

    const int nbv[8] = {nb0.x, nb0.y, nb0.z, nb0.w, nb1.x, nb1.y, nb1.z, nb1.w};
    const int mbits = (mk0.x == 1)        | ((mk0.y == 1) << 1) |
                      ((mk0.z == 1) << 2) | ((mk0.w == 1) << 3) |
                      ((mk1.x == 1) << 4) | ((mk1.y == 1) << 5) |
                      ((mk1.z == 1) << 6) | ((mk1.w == 1) << 7);

    const char* Tb = (const char*)T;
    const unsigned cb = (unsigned)c << 4;
    const unsigned qoff = ((unsigned)src << 9) + cb;   // q line: L1-hot anchor

    // Phase 1: score gathers, grouped issue. Masked rows -> q line (no new
    // cache lines; values arithmetically discarded).
    const f16x8 qh = *(const f16x8*)(Tb + qoff);
    f16x8 kh[8];
    #pragma unroll
    for (int ch = 0; ch < 8; ch++) {
        const unsigned o = ((mbits >> ch) & 1) ? (((unsigned)nbv[ch] << 9) + cb)
                                               : qoff;
        kh[ch] = *(const f16x8*)(Tb + o);
    }
    __builtin_amdgcn_sched_barrier(0);   // all 8 kh airborne before the dots

    float sc[8];
    #pragma unroll
    for (int ch = 0; ch < 8; ch++) {
        float d = 0.f;
        #pragma unroll
        for (int j = 0; j < 4; j++) {
            f16x2 qa; qa[0] = qh[2 * j];     qa[1] = qh[2 * j + 1];
            f16x2 ka; ka[0] = kh[ch][2 * j]; ka[1] = kh[ch][2 * j + 1];
            d = __builtin_amdgcn_fdot2(qa, ka, d, false);
        }
        // 16-lane butterfly sum, all-DPP.
        d = dpp_add<0xB1>(d);    // xor1
        d = dpp_add<0x4E>(d);    // xor2
        d = dpp_add<0x141>(d);   // 8-group exchange
        d = dpp_add<0x140>(d);   // 16-group exchange
        sc[ch] = ((mbits >> ch) & 1) ? d * 5.0f : -1e6f;
    }

    // Running max over 32 (8 regs x 4 r-groups).
    float mx = sc[0];
    #pragma unroll
    for (int ch = 1; ch < 8; ch++) mx = fmaxf(mx, sc[ch]);
    mx = fmaxf(mx, swz16(mx));
    mx = fmaxf(mx, __shfl_xor(mx, 32));

    // Unnormalized probs. Masked: exp(-1e6 - mx) == +0.0f. All-masked s:
    // exp(0) == 1 > PTHR for every ch, so the filter below loads the TRUE
    // neighbor rows and inv == rcp(32) (exact) gives the uniform mean.
    float p[8];
    float sum = 0.f;
    #pragma unroll
    for (int ch = 0; ch < 8; ch++) {
        p[ch] = __expf(sc[ch] - mx);
        sum += p[ch];
    }

    // Phase 2: agg gathers, issued BEFORE the softmax tail so the sum
    // butterfly + rcp hide their latency. Fetch filter: p <= PTHR rows
    // (masked, underflowed, or negligible) redirect to the q line -- zero
    // new cache lines; their contribution is dropped (error <= 5e-6).
    f16x8 vv[8];
    #pragma unroll
    for (int ch = 0; ch < 8; ch++) {
        const unsigned o = (p[ch] > PTHR) ? (((unsigned)nbv[ch] << 9) + cb + 256)
                                          : qoff;
        vv[ch] = *(const f16x8*)(Tb + o);
    }
    __builtin_amdgcn_sched_barrier(0);   // all 8 vv airborne before agg/tail

    sum += swz16(sum);
    sum += __shfl_xor(sum, 32);
    const float inv = __builtin_amdgcn_rcpf(sum);

    // Agg with UNNORMALIZED p; single scale by inv after the final butterfly.
    // Filtered channels must not touch acc (their vv is the q line): zero p.
    float acc[8] = {0.f, 0.f, 0.f, 0.f, 0.f, 0.f, 0.f, 0.f};
    #pragma unroll
    for (int ch = 0; ch < 8; ch++) {
        const float pc = (p[ch] > PTHR) ? p[ch] : 0.f;
        #pragma unroll
        for (int j = 0; j < 8; j++)
            acc[j] += pc * (float)vv[ch][j];
    }

    // Cross-group butterfly: sum the 4 r-group partials, then normalize.
    #pragma unroll
    for (int j = 0; j < 8; j++) {
        acc[j] += swz16(acc[j]);
        acc[j] += __shfl_xor(acc[j], 32);
        acc[j] *= inv;
    }

    // lane (r,c) writes cols c*8 + r*2 + {0,1}: contiguous 512 B per wave.
    *((float2*)(out + (size_t)src * CC) + c * 4 + r) =
        make_float2(acc[r * 2], acc[r * 2 + 1]);
}

extern "C" void kernel_launch(void* const* d_in, const int* in_sizes, int n_in,
                              void* d_out, int out_size, void* d_ws, size_t ws_size,
                              hipStream_t stream)
{
    const float* wv   = (const float*)d_in[0];
    const int*   src  = (const int*)d_in[1];
    const int*   nei  = (const int*)d_in[2];
    const int*   msk  = (const int*)d_in[3];
    const float* W    = (const float*)d_in[4];
    const float* bias = (const float*)d_in[5];
    float* out = (float*)d_out;
    _Float16* T = (_Float16*)d_ws;   // 100000 * 512 B = 51.2 MB

    proj_kernel<<<NN / RPB, 256, 0, stream>>>(wv, W, bias, T, out);           // 625
    attn_kernel<<<(SS * 64) / 256, 256, 0, stream>>>(T, src, nei, msk, out);  // 12500
}